// Round 1
// 3345.060 us; speedup vs baseline: 1.0632x; 1.0632x over previous
//
#include <hip/hip_runtime.h>
#include <hip/hip_bf16.h>
#include <math.h>

// Shapes (fixed): B=8, L=512, D=768, H=12, DK=64, N=B*L=4096, BH=96
// Output layout (floats): context[37748736] | d[25165824] | d0[49152] | loss[1]
// Scratch plan: Q,K, LL(Mv), and Mp panel-row scratch live inside the context
// output region (fully overwritten by context_mfma_kernel at the end).
// d region holds A until finalize_d converts it in place to d.
// d_ws holds tiny arrays (R, m, colsum, diag) ~0.42 MB.
//
// R0 change: context GEMM moved to bf16 MFMA with hi/lo split (3 products:
// hh, hl, lh) for fp32-level accuracy at matrix-core rate. Everything else
// unchanged.

#define INV_SQRT_D 0.03608439182435161f  // 1/sqrt(768)

typedef short bf16x8 __attribute__((ext_vector_type(8)));
typedef float f32x4 __attribute__((ext_vector_type(4)));
typedef unsigned int u32x4 __attribute__((ext_vector_type(4)));

// ---------------------------------------------------------------------------
// 8x8-per-thread fp32 GEMM micro kernel over a K-chunk of 16.
// At[t][r] (r = output row), Bt[t][c] (c = output col), both row stride 132.
__device__ __forceinline__ void mm_micro(const float* At, const float* Bt,
                                         float acc[8][8], int tx, int ty)
{
#pragma unroll
  for (int t = 0; t < 16; ++t) {
    const float4 a0 = *(const float4*)(At + t*132 + ty*8);
    const float4 a1 = *(const float4*)(At + t*132 + ty*8 + 4);
    const float4 b0 = *(const float4*)(Bt + t*132 + tx*8);
    const float4 b1 = *(const float4*)(Bt + t*132 + tx*8 + 4);
    const float a[8] = {a0.x,a0.y,a0.z,a0.w,a1.x,a1.y,a1.z,a1.w};
    const float b[8] = {b0.x,b0.y,b0.z,b0.w,b1.x,b1.y,b1.z,b1.w};
#pragma unroll
    for (int i = 0; i < 8; ++i)
#pragma unroll
      for (int j = 0; j < 8; ++j)
        acc[i][j] = fmaf(a[i], b[j], acc[i][j]);
  }
}

// ---------------------------------------------------------------------------
// Q = (x@Wq + bq)/sqrt(D), K = x@Wk + bk.   out tiles 128x128, block 256.
__global__ __launch_bounds__(256) void proj_kernel(
    const float* __restrict__ x,
    const float* __restrict__ Wq, const float* __restrict__ bq,
    const float* __restrict__ Wk, const float* __restrict__ bk,
    float* __restrict__ Q, float* __restrict__ Kc)
{
  const float* W; const float* bias; float* out; float scale;
  if (blockIdx.z == 0) { W = Wq; bias = bq; out = Q;  scale = INV_SQRT_D; }
  else                 { W = Wk; bias = bk; out = Kc; scale = 1.0f; }

  __shared__ __align__(16) float At[16*132];
  __shared__ __align__(16) float Bt[16*132];

  const int tx = threadIdx.x, ty = threadIdx.y;
  const int tid = ty*16 + tx;
  const int row0 = blockIdx.y * 128, col0 = blockIdx.x * 128;
  const int lt = tid & 15, lr = tid >> 4;
  const int bc = tid & 127, btr = tid >> 7;

  float acc[8][8] = {};

  for (int kk = 0; kk < 768; kk += 16) {
#pragma unroll
    for (int u = 0; u < 8; ++u) {
      const int r = lr + 16*u;
      At[lt*132 + r] = x[(size_t)(row0 + r)*768 + kk + lt];
    }
#pragma unroll
    for (int u = 0; u < 8; ++u) {
      const int t = btr + 2*u;
      Bt[t*132 + bc] = W[(size_t)(kk + t)*768 + col0 + bc];
    }
    __syncthreads();
    mm_micro(At, Bt, acc, tx, ty);
    __syncthreads();
  }

#pragma unroll
  for (int i = 0; i < 8; ++i) {
    const int r = row0 + ty*8 + i;
#pragma unroll
    for (int j = 0; j < 8; j += 4) {
      const int c = col0 + tx*8 + j;
      float4 v;
      v.x = (acc[i][j+0] + bias[c+0]) * scale;
      v.y = (acc[i][j+1] + bias[c+1]) * scale;
      v.z = (acc[i][j+2] + bias[c+2]) * scale;
      v.w = (acc[i][j+3] + bias[c+3]) * scale;
      *(float4*)(out + (size_t)r*768 + c) = v;
    }
  }
}

// ---------------------------------------------------------------------------
// root = x@Wr + br; m = mask/-10000; R = exp(max(root - m*50, -40)).
__global__ __launch_bounds__(256) void root_kernel(
    const float* __restrict__ x, const float* __restrict__ Wr,
    const float* __restrict__ br, const float* __restrict__ mask,
    float* __restrict__ Rv, float* __restrict__ mv)
{
  const int n = blockIdx.x*4 + (threadIdx.x >> 6);
  const int lane = threadIdx.x & 63;
  float s = 0.0f;
  for (int c = lane; c < 768; c += 64) s += x[(size_t)n*768 + c] * Wr[c];
#pragma unroll
  for (int off = 32; off > 0; off >>= 1) s += __shfl_down(s, off, 64);
  if (lane == 0) {
    const float root = s + br[0];
    const float m = mask[n] * (-1e-4f);
    Rv[n] = expf(fmaxf(root - m*50.0f, -40.0f));
    mv[n] = m;
  }
}

// ---------------------------------------------------------------------------
// A[bh][i][j] = exp(max(q_i . k_j - (m_i+m_j)*50, -40)).  tiles 128x128, K=64.
__global__ __launch_bounds__(256) void scores_kernel(
    const float* __restrict__ Qs, const float* __restrict__ Ks,
    const float* __restrict__ mv, float* __restrict__ A)
{
  const int bh = blockIdx.z, b = bh / 12, h = bh % 12;
  const int i0 = blockIdx.y * 128, j0 = blockIdx.x * 128;
  __shared__ __align__(16) float At[16*132];
  __shared__ __align__(16) float Bt[16*132];
  const int tx = threadIdx.x, ty = threadIdx.y;
  const int tid = ty*16 + tx;
  const int lt = tid & 15, lr = tid >> 4;
  const size_t qbase = (size_t)(b*512 + i0)*768 + h*64;
  const size_t kbase = (size_t)(b*512 + j0)*768 + h*64;

  float acc[8][8] = {};

  for (int kk = 0; kk < 64; kk += 16) {
#pragma unroll
    for (int u = 0; u < 8; ++u) {
      const int r = lr + 16*u;
      At[lt*132 + r] = Qs[qbase + (size_t)r*768 + kk + lt];
      Bt[lt*132 + r] = Ks[kbase + (size_t)r*768 + kk + lt];
    }
    __syncthreads();
    mm_micro(At, Bt, acc, tx, ty);
    __syncthreads();
  }

  float mi[8], mj[8];
#pragma unroll
  for (int i = 0; i < 8; ++i) mi[i] = mv[b*512 + i0 + ty*8 + i];
#pragma unroll
  for (int j = 0; j < 8; ++j) mj[j] = mv[b*512 + j0 + tx*8 + j];

#pragma unroll
  for (int i = 0; i < 8; ++i) {
    const size_t rowb = (size_t)(bh*512 + i0 + ty*8 + i)*512;
#pragma unroll
    for (int j = 0; j < 8; j += 4) {
      float4 v;
      v.x = expf(fmaxf(acc[i][j+0] - (mi[i]+mj[j+0])*50.0f, -40.0f));
      v.y = expf(fmaxf(acc[i][j+1] - (mi[i]+mj[j+1])*50.0f, -40.0f));
      v.z = expf(fmaxf(acc[i][j+2] - (mi[i]+mj[j+2])*50.0f, -40.0f));
      v.w = expf(fmaxf(acc[i][j+3] - (mi[i]+mj[j+3])*50.0f, -40.0f));
      *(float4*)(A + rowb + j0 + tx*8 + j) = v;
    }
  }
}

// ---------------------------------------------------------------------------
// colsum[bh][j] = sum_i A[bh][i][j]
__global__ void colsum_kernel(const float* __restrict__ A, float* __restrict__ colsum)
{
  const int bh = blockIdx.y;
  const int j = blockIdx.x*256 + threadIdx.x;
  const float* Ab = A + (size_t)bh*262144;
  float s = 0.0f;
  for (int i = 0; i < 512; ++i) s += Ab[(size_t)i*512 + j];
  colsum[bh*512 + j] = s;
}

// ---------------------------------------------------------------------------
// M = diag(colsum + R) - A
__global__ void buildM_kernel(const float* __restrict__ A, const float* __restrict__ colsum,
                              const float* __restrict__ Rv, float* __restrict__ M)
{
  const size_t g = ((size_t)blockIdx.x*256 + threadIdx.x)*4;
  const int bh = (int)(g >> 18);
  const int i = (int)((g >> 9) & 511);
  const int j = (int)(g & 511);
  const float4 a = *(const float4*)(A + g);
  float4 v; v.x = -a.x; v.y = -a.y; v.z = -a.z; v.w = -a.w;
  if (i >= j && i < j+4) {
    const float dadd = colsum[bh*512 + i] + Rv[(bh/12)*512 + i];
    ((float*)&v)[i - j] += dadd;
  }
  *(float4*)(M + g) = v;
}

// ---------------------------------------------------------------------------
// Blocked Gauss-Jordan, NB=64, split per step into panel + update kernels.
__global__ __launch_bounds__(512) void gj_panel_kernel(
    float* __restrict__ M, float* __restrict__ Mp, int k0)
{
  float* const Mg  = M  + (size_t)blockIdx.x * 262144;
  float* const Mpg = Mp + (size_t)blockIdx.x * 32768;
  const int tid = threadIdx.x;

  // ---- copy panel rows (old values) to scratch: 16 passes x 512 threads ----
  {
    const int c = (tid & 127) * 4;
    const int rsub = tid >> 7;           // 0..3
#pragma unroll
    for (int p = 0; p < 16; ++p) {
      const int r = p*4 + rsub;          // 0..63
      *(float4*)(Mpg + (size_t)r*512 + c) =
          *(const float4*)(Mg + (size_t)(k0 + r)*512 + c);
    }
  }

  // ---- load my panel row into registers ----
  const int i = tid;                      // one row per thread
  float w[64];
  {
    const float* src = Mg + (size_t)i*512 + k0;
#pragma unroll
    for (int q = 0; q < 16; ++q) {
      const float4 t4 = *(const float4*)(src + q*4);
      w[q*4+0]=t4.x; w[q*4+1]=t4.y; w[q*4+2]=t4.z; w[q*4+3]=t4.w;
    }
  }

  __shared__ __align__(16) float rowbuf[2][64];

#pragma unroll 1
  for (int kk = 0; kk < 64; ++kk) {
    const int b = kk & 1;
    const int krow = k0 + kk;
    if (i == krow) {
      float4* rb = (float4*)rowbuf[b];
#pragma unroll
      for (int q = 0; q < 16; ++q)
        rb[q] = make_float4(w[q*4+0], w[q*4+1], w[q*4+2], w[q*4+3]);
    }
    // f = w[kk] (thread-local, dynamic index -> select chain; overlaps barrier)
    float f = w[0];
#pragma unroll
    for (int j = 1; j < 64; ++j) if (j == kk) f = w[j];
    __syncthreads();
    const float p  = 1.0f / rowbuf[b][kk];
    const float fp = f * p;
    if (i == krow) {
#pragma unroll
      for (int j = 0; j < 64; ++j)
        w[j] = (j == kk) ? p : w[j] * p;
    } else {
#pragma unroll
      for (int j = 0; j < 64; ++j)
        w[j] = (j == kk) ? (-fp) : fmaf(-fp, rowbuf[b][j], w[j]);
    }
    // no second barrier: next pivot writes the OTHER rowbuf buffer
  }

  // ---- write W back into panel columns ----
  {
    float* dst = Mg + (size_t)i*512 + k0;
#pragma unroll
    for (int q = 0; q < 16; ++q)
      *(float4*)(dst + q*4) = make_float4(w[q*4+0], w[q*4+1], w[q*4+2], w[q*4+3]);
  }
}

// Update: M[i][j] = (i in P ? 0 : M_old[i][j]) + W[i][:] . Mp_old[:][j]
__global__ __launch_bounds__(256) void gj_update_kernel(
    float* __restrict__ M, const float* __restrict__ Mp, int k0)
{
  const int bh = blockIdx.z;
  const int row0 = blockIdx.y * 128, col0 = blockIdx.x * 128;
  float* const Mg = M + (size_t)bh*262144;
  const float* const Mpg = Mp + (size_t)bh*32768;

  __shared__ __align__(16) float At[16*132];
  __shared__ __align__(16) float Bt[16*132];
  const int tx = threadIdx.x, ty = threadIdx.y;
  const int tid = ty*16 + tx;
  const int lt = tid & 15, lr = tid >> 4;
  const int bc = tid & 127, btr = tid >> 7;

  float acc[8][8] = {};

  for (int kc = 0; kc < 64; kc += 16) {
#pragma unroll
    for (int u = 0; u < 8; ++u) {
      const int r = lr + 16*u;
      At[lt*132 + r] = Mg[(size_t)(row0 + r)*512 + k0 + kc + lt];     // W slice
    }
#pragma unroll
    for (int u = 0; u < 8; ++u) {
      const int t = btr + 2*u;
      Bt[t*132 + bc] = Mpg[(size_t)(kc + t)*512 + col0 + bc];         // Mp_old
    }
    __syncthreads();
    mm_micro(At, Bt, acc, tx, ty);
    __syncthreads();
  }

#pragma unroll
  for (int ii = 0; ii < 8; ++ii) {
    const int irow = row0 + ty*8 + ii;
    const bool inP = (irow >= k0) && (irow < k0 + 64);
#pragma unroll
    for (int jj = 0; jj < 8; jj += 4) {
      const int jcol = col0 + tx*8 + jj;
      if (jcol >= k0 && jcol < k0 + 64) continue;   // panel cols hold W
      float* cell = Mg + (size_t)irow*512 + jcol;
      float4 v = make_float4(acc[ii][jj+0], acc[ii][jj+1], acc[ii][jj+2], acc[ii][jj+3]);
      if (!inP) {
        const float4 o = *(const float4*)cell;
        v.x += o.x; v.y += o.y; v.z += o.z; v.w += o.w;
      }
      *(float4*)cell = v;
    }
  }
}

// ---------------------------------------------------------------------------
// diag = diag(LLinv); d0 = R * diag
__global__ void diag_d0_kernel(const float* __restrict__ Minv, const float* __restrict__ Rv,
                               float* __restrict__ diagv, float* __restrict__ d0)
{
  const int bh = blockIdx.x, l = threadIdx.x;
  const float dg = Minv[(size_t)bh*262144 + (size_t)l*513];
  diagv[bh*512 + l] = dg;
  d0[bh*512 + l] = Rv[(bh/12)*512 + l] * dg;
}

// ---------------------------------------------------------------------------
// loss = mean_n( label_n * sum_h -log(clip(d0[b,h,l], 1e-5, 1-1e-5)) )
__global__ __launch_bounds__(1024) void loss_kernel(const float* __restrict__ d0,
                                                    const int* __restrict__ labels,
                                                    float* __restrict__ loss)
{
  float acc = 0.0f;
  for (int n = threadIdx.x; n < 4096; n += 1024) {
    if (labels[n] != 0) {
      const int b = n >> 9, l = n & 511;
      float s = 0.0f;
#pragma unroll
      for (int h = 0; h < 12; ++h) {
        float p = d0[(size_t)(b*12 + h)*512 + l];
        p = fminf(fmaxf(p, 1e-5f), 1.0f - 1e-5f);
        s -= logf(p);
      }
      acc += s;
    }
  }
  __shared__ float red[16];
#pragma unroll
  for (int off = 32; off > 0; off >>= 1) acc += __shfl_down(acc, off, 64);
  const int wv = threadIdx.x >> 6, ln = threadIdx.x & 63;
  if (ln == 0) red[wv] = acc;
  __syncthreads();
  if (threadIdx.x == 0) {
    float t = 0.0f;
    for (int w2 = 0; w2 < 16; ++w2) t += red[w2];
    loss[0] = t * (1.0f/4096.0f);
  }
}

// ---------------------------------------------------------------------------
// d[i][j] = A[i][j] * (diag[j] - LLinv[j][i])   (in place over A)
__global__ __launch_bounds__(256) void finalize_d_kernel(
    float* __restrict__ dmat, const float* __restrict__ Minv, const float* __restrict__ diagv)
{
  const int bh = blockIdx.z;
  const int i0 = blockIdx.y*64, j0 = blockIdx.x*64;
  __shared__ float t[64][65];
  const int tx = threadIdx.x, ty = threadIdx.y;
  const size_t mbase = (size_t)bh*262144;
  for (int jj = ty; jj < 64; jj += 4)
    t[jj][tx] = Minv[mbase + (size_t)(j0+jj)*512 + i0 + tx];
  __syncthreads();
  const float dg_j = diagv[bh*512 + j0 + tx];
  for (int ii = ty; ii < 64; ii += 4) {
    const size_t idx = mbase + (size_t)(i0+ii)*512 + j0 + tx;
    dmat[idx] = dmat[idx] * (dg_j - t[tx][ii]);
  }
}

// ---------------------------------------------------------------------------
// context[b,h,q,:] = sum_k attn[q,k] * x[b,k,:],  attn[q,k] = masked d[k,q]
// MFMA version: bf16 hi/lo split, 3 products (hh, hl, lh) per 16x16x32 tile.
// LDS tiles are [k(32)][col(128)] with row stride 133 u32 (odd stride:
// per-e frag reads land <=2-way on banks); each u32 packs (hi | lo<<16).
// Fragment k-slot order is the same construction for A and B, so any
// internal k permutation of the MFMA cancels. C/D map: col=lane&15,
// row=(lane>>4)*4+reg (HW-verified).
__device__ __forceinline__ unsigned int pack_bf16x2(float v)
{
  const unsigned int u = __float_as_uint(v);
  const unsigned int hi = (u + 0x7FFFu + ((u >> 16) & 1u)) >> 16;  // RNE bf16(v)
  const float hf = __uint_as_float(hi << 16);
  const unsigned int lo = __float_as_uint(v - hf) >> 16;           // trunc bf16(residual)
  return hi | (lo << 16);
}

__global__ __launch_bounds__(256) void context_mfma_kernel(
    const float* __restrict__ dmat, const float* __restrict__ x,
    const float* __restrict__ mv, float* __restrict__ ctx)
{
  const int bh = blockIdx.z, b = bh / 12;
  const int q0 = blockIdx.y << 7;          // 0..384
  const int c0 = blockIdx.x << 7;          // 0..640

  __shared__ unsigned int As[32*133];      // packed (hi|lo) of masked d^T tile cols
  __shared__ unsigned int Bs[32*133];      // packed (hi|lo) of x tile cols

  const int tid = threadIdx.x;
  const int w = tid >> 6, l = tid & 63;
  const int wq = w >> 1, wc = w & 1;       // wave -> 64x64 quadrant
  const int l15 = l & 15, g = l >> 4;      // MFMA lane coords
  const int q4 = tid & 31, kr0 = tid >> 5; // staging coords

  const size_t dbase = (size_t)bh*262144;
  const size_t xbase = (size_t)b*393216;   // 512*768

  float mq[4];
  {
    const float4 t4 = *(const float4*)(mv + b*512 + q0 + q4*4);
    mq[0]=t4.x; mq[1]=t4.y; mq[2]=t4.z; mq[3]=t4.w;
  }

  f32x4 acc[4][4] = {};

  for (int kk = 0; kk < 512; kk += 32) {
    __syncthreads();                       // previous iter's frag reads done
#pragma unroll
    for (int p = 0; p < 4; ++p) {
      const int kr = kr0 + 8*p;
      const int krow = kk + kr;
      const float mk = mv[b*512 + krow];
      const float4 av = *(const float4*)(dmat + dbase + (size_t)krow*512 + q0 + q4*4);
      const float4 bv = *(const float4*)(x + xbase + (size_t)krow*768 + c0 + q4*4);
      unsigned int* aw = As + kr*133 + q4*4;
      unsigned int* bw = Bs + kr*133 + q4*4;
      aw[0] = pack_bf16x2(((mk + mq[0]) != 0.0f) ? 0.0f : av.x);
      aw[1] = pack_bf16x2(((mk + mq[1]) != 0.0f) ? 0.0f : av.y);
      aw[2] = pack_bf16x2(((mk + mq[2]) != 0.0f) ? 0.0f : av.z);
      aw[3] = pack_bf16x2(((mk + mq[3]) != 0.0f) ? 0.0f : av.w);
      bw[0] = pack_bf16x2(bv.x);
      bw[1] = pack_bf16x2(bv.y);
      bw[2] = pack_bf16x2(bv.z);
      bw[3] = pack_bf16x2(bv.w);
    }
    __syncthreads();

    u32x4 ah[4], al[4], bhv[4], blv[4];
#pragma unroll
    for (int mi = 0; mi < 4; ++mi) {
      const unsigned int* base = As + g*8*133 + (wq*64 + mi*16 + l15);
      unsigned int u[8];
#pragma unroll
      for (int e = 0; e < 8; ++e) u[e] = base[e*133];
#pragma unroll
      for (int d2 = 0; d2 < 4; ++d2) {
        ah[mi][d2] = __builtin_amdgcn_perm(u[2*d2+1], u[2*d2], 0x05040100u);
        al[mi][d2] = __builtin_amdgcn_perm(u[2*d2+1], u[2*d2], 0x07060302u);
      }
    }
#pragma unroll
    for (int ni = 0; ni < 4; ++ni) {
      const unsigned int* base = Bs + g*8*133 + (wc*64 + ni*16 + l15);
      unsigned int u[8];
#pragma unroll
      for (int e = 0; e < 8; ++e) u[e] = base[e*133];
#pragma unroll
      for (int d2 = 0; d2 < 4; ++d2) {
        bhv[ni][d2] = __builtin_amdgcn_perm(u[2*d2+1], u[2*d2], 0x05040100u);
        blv[ni][d2] = __builtin_amdgcn_perm(u[2*d2+1], u[2*d2], 0x07060302u);
      }
    }

#pragma unroll
    for (int mi = 0; mi < 4; ++mi) {
      const bf16x8 Ah = __builtin_bit_cast(bf16x8, ah[mi]);
      const bf16x8 Al = __builtin_bit_cast(bf16x8, al[mi]);
#pragma unroll
      for (int ni = 0; ni < 4; ++ni) {
        const bf16x8 Bh = __builtin_bit_cast(bf16x8, bhv[ni]);
        const bf16x8 Bl = __builtin_bit_cast(bf16x8, blv[ni]);
        acc[mi][ni] = __builtin_amdgcn_mfma_f32_16x16x32_bf16(Ah, Bh, acc[mi][ni], 0, 0, 0);
        acc[mi][ni] = __builtin_amdgcn_mfma_f32_16x16x32_bf16(Ah, Bl, acc[mi][ni], 0, 0, 0);
        acc[mi][ni] = __builtin_amdgcn_mfma_f32_16x16x32_bf16(Al, Bh, acc[mi][ni], 0, 0, 0);
      }
    }
  }

#pragma unroll
  for (int mi = 0; mi < 4; ++mi) {
    const int row = q0 + wq*64 + mi*16 + g*4;
#pragma unroll
    for (int ni = 0; ni < 4; ++ni) {
      const int col = c0 + wc*64 + ni*16 + l15;
#pragma unroll
      for (int r = 0; r < 4; ++r)
        ctx[((size_t)bh*512 + row + r)*768 + col] = acc[mi][ni][r];
    }
  }
}

// ---------------------------------------------------------------------------
extern "C" void kernel_launch(void* const* d_in, const int* in_sizes, int n_in,
                              void* d_out, int out_size, void* d_ws, size_t ws_size,
                              hipStream_t stream)
{
  (void)in_sizes; (void)n_in; (void)out_size; (void)ws_size;

  const float* x    = (const float*)d_in[0];
  const float* mask = (const float*)d_in[1];
  const int*   roots= (const int*)d_in[2];
  const float* Wq   = (const float*)d_in[4];
  const float* bq   = (const float*)d_in[5];
  const float* Wk   = (const float*)d_in[6];
  const float* bk   = (const float*)d_in[7];
  const float* Wr   = (const float*)d_in[8];
  const float* br   = (const float*)d_in[9];

  float* out        = (float*)d_out;
  float* ctx_region = out;                 // 37748736 floats
  float* d_region   = out + 37748736;      // 25165824 floats (A -> d in place)
  float* d0_region  = out + 62914560;      // 49152 floats
  float* loss_ptr   = out + 62963712;      // 1 float

  // scratch inside the context region (overwritten by context_mfma at the end)
  float* Qs = ctx_region;                  // 3145728
  float* Ks = ctx_region + 3145728;        // 3145728
  float* Mv = ctx_region + 6291456;        // 25165824 (ends at 31457280)
  float* Mp = ctx_region + 31457280;       // 3145728  (ends at 34603008 < 37748736)

  float* ws     = (float*)d_ws;
  float* Rv     = ws;                      // 4096
  float* mv     = ws + 4096;               // 4096
  float* colsum = ws + 8192;               // 49152
  float* diagv  = ws + 57344;              // 49152

  proj_kernel   <<<dim3(6,32,2),  dim3(16,16), 0, stream>>>(x, Wq, bq, Wk, bk, Qs, Ks);
  root_kernel   <<<dim3(1024),    dim3(256),   0, stream>>>(x, Wr, br, mask, Rv, mv);
  scores_kernel <<<dim3(4,4,96),  dim3(16,16), 0, stream>>>(Qs, Ks, mv, d_region);
  colsum_kernel <<<dim3(2,96),    dim3(256),   0, stream>>>(d_region, colsum);
  buildM_kernel <<<dim3(24576),   dim3(256),   0, stream>>>(d_region, colsum, Rv, Mv);

  for (int step = 0; step < 8; ++step) {
    const int k0 = step * 64;
    gj_panel_kernel <<<dim3(96),     dim3(512),   0, stream>>>(Mv, Mp, k0);
    gj_update_kernel<<<dim3(4,4,96), dim3(16,16), 0, stream>>>(Mv, Mp, k0);
  }

  diag_d0_kernel<<<dim3(96),      dim3(512),   0, stream>>>(Mv, Rv, diagv, d0_region);
  loss_kernel   <<<dim3(1),       dim3(1024),  0, stream>>>(d0_region, roots, loss_ptr);
  finalize_d_kernel<<<dim3(8,8,96), dim3(64,4), 0, stream>>>(d_region, Mv, diagv);
  context_mfma_kernel<<<dim3(6,4,96), dim3(256), 0, stream>>>(d_region, x, mv, ctx_region);
}

// Round 2
// 1902.299 us; speedup vs baseline: 1.8695x; 1.7584x over previous
//
#include <hip/hip_runtime.h>
#include <hip/hip_bf16.h>
#include <math.h>

// Shapes (fixed): B=8, L=512, D=768, H=12, DK=64, N=B*L=4096, BH=96
// Output layout (floats): context[37748736] | d[25165824] | d0[49152] | loss[1]
// Scratch plan: Q,K, LL(Mv), Mp panel-row scratch, and Inv (A11^-1 blocks)
// live inside the context output region (fully overwritten by
// context_mfma_kernel at the end). d region holds A until finalize_d converts
// it in place to d. d_ws holds tiny arrays (R, m, colsum, diag) ~0.42 MB.
//
// R1 change: gj_panel_kernel (286us x8, 68% of runtime, barrier-serialized)
// replaced by algebraic decomposition: W = [A11^-1 ; -A21*A11^-1].
//   gj_inv_kernel : wave-synchronous 64x64 register inversion (no barriers)
//                   + concurrent Mp copy by the other 3 waves.
//   gj_w_kernel   : small blocked GEMM writes W into panel columns.
//   gj_update_kernel unchanged.

#define INV_SQRT_D 0.03608439182435161f  // 1/sqrt(768)

typedef short bf16x8 __attribute__((ext_vector_type(8)));
typedef float f32x4 __attribute__((ext_vector_type(4)));
typedef unsigned int u32x4 __attribute__((ext_vector_type(4)));

// ---------------------------------------------------------------------------
// 8x8-per-thread fp32 GEMM micro kernel over a K-chunk of 16.
// At[t][r] (r = output row), Bt[t][c] (c = output col), both row stride 132.
__device__ __forceinline__ void mm_micro(const float* At, const float* Bt,
                                         float acc[8][8], int tx, int ty)
{
#pragma unroll
  for (int t = 0; t < 16; ++t) {
    const float4 a0 = *(const float4*)(At + t*132 + ty*8);
    const float4 a1 = *(const float4*)(At + t*132 + ty*8 + 4);
    const float4 b0 = *(const float4*)(Bt + t*132 + tx*8);
    const float4 b1 = *(const float4*)(Bt + t*132 + tx*8 + 4);
    const float a[8] = {a0.x,a0.y,a0.z,a0.w,a1.x,a1.y,a1.z,a1.w};
    const float b[8] = {b0.x,b0.y,b0.z,b0.w,b1.x,b1.y,b1.z,b1.w};
#pragma unroll
    for (int i = 0; i < 8; ++i)
#pragma unroll
      for (int j = 0; j < 8; ++j)
        acc[i][j] = fmaf(a[i], b[j], acc[i][j]);
  }
}

// ---------------------------------------------------------------------------
// Q = (x@Wq + bq)/sqrt(D), K = x@Wk + bk.   out tiles 128x128, block 256.
__global__ __launch_bounds__(256) void proj_kernel(
    const float* __restrict__ x,
    const float* __restrict__ Wq, const float* __restrict__ bq,
    const float* __restrict__ Wk, const float* __restrict__ bk,
    float* __restrict__ Q, float* __restrict__ Kc)
{
  const float* W; const float* bias; float* out; float scale;
  if (blockIdx.z == 0) { W = Wq; bias = bq; out = Q;  scale = INV_SQRT_D; }
  else                 { W = Wk; bias = bk; out = Kc; scale = 1.0f; }

  __shared__ __align__(16) float At[16*132];
  __shared__ __align__(16) float Bt[16*132];

  const int tx = threadIdx.x, ty = threadIdx.y;
  const int tid = ty*16 + tx;
  const int row0 = blockIdx.y * 128, col0 = blockIdx.x * 128;
  const int lt = tid & 15, lr = tid >> 4;
  const int bc = tid & 127, btr = tid >> 7;

  float acc[8][8] = {};

  for (int kk = 0; kk < 768; kk += 16) {
#pragma unroll
    for (int u = 0; u < 8; ++u) {
      const int r = lr + 16*u;
      At[lt*132 + r] = x[(size_t)(row0 + r)*768 + kk + lt];
    }
#pragma unroll
    for (int u = 0; u < 8; ++u) {
      const int t = btr + 2*u;
      Bt[t*132 + bc] = W[(size_t)(kk + t)*768 + col0 + bc];
    }
    __syncthreads();
    mm_micro(At, Bt, acc, tx, ty);
    __syncthreads();
  }

#pragma unroll
  for (int i = 0; i < 8; ++i) {
    const int r = row0 + ty*8 + i;
#pragma unroll
    for (int j = 0; j < 8; j += 4) {
      const int c = col0 + tx*8 + j;
      float4 v;
      v.x = (acc[i][j+0] + bias[c+0]) * scale;
      v.y = (acc[i][j+1] + bias[c+1]) * scale;
      v.z = (acc[i][j+2] + bias[c+2]) * scale;
      v.w = (acc[i][j+3] + bias[c+3]) * scale;
      *(float4*)(out + (size_t)r*768 + c) = v;
    }
  }
}

// ---------------------------------------------------------------------------
// root = x@Wr + br; m = mask/-10000; R = exp(max(root - m*50, -40)).
__global__ __launch_bounds__(256) void root_kernel(
    const float* __restrict__ x, const float* __restrict__ Wr,
    const float* __restrict__ br, const float* __restrict__ mask,
    float* __restrict__ Rv, float* __restrict__ mv)
{
  const int n = blockIdx.x*4 + (threadIdx.x >> 6);
  const int lane = threadIdx.x & 63;
  float s = 0.0f;
  for (int c = lane; c < 768; c += 64) s += x[(size_t)n*768 + c] * Wr[c];
#pragma unroll
  for (int off = 32; off > 0; off >>= 1) s += __shfl_down(s, off, 64);
  if (lane == 0) {
    const float root = s + br[0];
    const float m = mask[n] * (-1e-4f);
    Rv[n] = expf(fmaxf(root - m*50.0f, -40.0f));
    mv[n] = m;
  }
}

// ---------------------------------------------------------------------------
// A[bh][i][j] = exp(max(q_i . k_j - (m_i+m_j)*50, -40)).  tiles 128x128, K=64.
__global__ __launch_bounds__(256) void scores_kernel(
    const float* __restrict__ Qs, const float* __restrict__ Ks,
    const float* __restrict__ mv, float* __restrict__ A)
{
  const int bh = blockIdx.z, b = bh / 12, h = bh % 12;
  const int i0 = blockIdx.y * 128, j0 = blockIdx.x * 128;
  __shared__ __align__(16) float At[16*132];
  __shared__ __align__(16) float Bt[16*132];
  const int tx = threadIdx.x, ty = threadIdx.y;
  const int tid = ty*16 + tx;
  const int lt = tid & 15, lr = tid >> 4;
  const size_t qbase = (size_t)(b*512 + i0)*768 + h*64;
  const size_t kbase = (size_t)(b*512 + j0)*768 + h*64;

  float acc[8][8] = {};

  for (int kk = 0; kk < 64; kk += 16) {
#pragma unroll
    for (int u = 0; u < 8; ++u) {
      const int r = lr + 16*u;
      At[lt*132 + r] = Qs[qbase + (size_t)r*768 + kk + lt];
      Bt[lt*132 + r] = Ks[kbase + (size_t)r*768 + kk + lt];
    }
    __syncthreads();
    mm_micro(At, Bt, acc, tx, ty);
    __syncthreads();
  }

  float mi[8], mj[8];
#pragma unroll
  for (int i = 0; i < 8; ++i) mi[i] = mv[b*512 + i0 + ty*8 + i];
#pragma unroll
  for (int j = 0; j < 8; ++j) mj[j] = mv[b*512 + j0 + tx*8 + j];

#pragma unroll
  for (int i = 0; i < 8; ++i) {
    const size_t rowb = (size_t)(bh*512 + i0 + ty*8 + i)*512;
#pragma unroll
    for (int j = 0; j < 8; j += 4) {
      float4 v;
      v.x = expf(fmaxf(acc[i][j+0] - (mi[i]+mj[j+0])*50.0f, -40.0f));
      v.y = expf(fmaxf(acc[i][j+1] - (mi[i]+mj[j+1])*50.0f, -40.0f));
      v.z = expf(fmaxf(acc[i][j+2] - (mi[i]+mj[j+2])*50.0f, -40.0f));
      v.w = expf(fmaxf(acc[i][j+3] - (mi[i]+mj[j+3])*50.0f, -40.0f));
      *(float4*)(A + rowb + j0 + tx*8 + j) = v;
    }
  }
}

// ---------------------------------------------------------------------------
// colsum[bh][j] = sum_i A[bh][i][j]
__global__ void colsum_kernel(const float* __restrict__ A, float* __restrict__ colsum)
{
  const int bh = blockIdx.y;
  const int j = blockIdx.x*256 + threadIdx.x;
  const float* Ab = A + (size_t)bh*262144;
  float s = 0.0f;
  for (int i = 0; i < 512; ++i) s += Ab[(size_t)i*512 + j];
  colsum[bh*512 + j] = s;
}

// ---------------------------------------------------------------------------
// M = diag(colsum + R) - A
__global__ void buildM_kernel(const float* __restrict__ A, const float* __restrict__ colsum,
                              const float* __restrict__ Rv, float* __restrict__ M)
{
  const size_t g = ((size_t)blockIdx.x*256 + threadIdx.x)*4;
  const int bh = (int)(g >> 18);
  const int i = (int)((g >> 9) & 511);
  const int j = (int)(g & 511);
  const float4 a = *(const float4*)(A + g);
  float4 v; v.x = -a.x; v.y = -a.y; v.z = -a.z; v.w = -a.w;
  if (i >= j && i < j+4) {
    const float dadd = colsum[bh*512 + i] + Rv[(bh/12)*512 + i];
    ((float*)&v)[i - j] += dadd;
  }
  *(float4*)(M + g) = v;
}

// ---------------------------------------------------------------------------
// GJ step decomposition. For panel P = cols/rows k0..k0+63:
//   W[panel rows]     = A11^-1
//   W[off-panel rows] = -M[off,P] * A11^-1
// gj_inv: wave0 inverts A11 (64x64) in registers (lane = row, no barriers,
// shuffle broadcasts); threads 64..255 copy old panel rows to Mp.
__global__ __launch_bounds__(256) void gj_inv_kernel(
    const float* __restrict__ M, float* __restrict__ Mp,
    float* __restrict__ Inv, int k0)
{
  const float* const Mg  = M   + (size_t)blockIdx.x * 262144;
  float* const Mpg       = Mp  + (size_t)blockIdx.x * 32768;
  float* const Ig        = Inv + (size_t)blockIdx.x * 4096;
  const int tid = threadIdx.x;

  if (tid >= 64) {
    // copy old panel rows -> Mp: 8192 float4s, 192 threads
    const int t = tid - 64;
    for (int p = 0; p < 43; ++p) {
      const int idx = p*192 + t;
      if (idx < 8192) {
        const int r = idx >> 7, c = (idx & 127) * 4;
        *(float4*)(Mpg + (size_t)r*512 + c) =
            *(const float4*)(Mg + (size_t)(k0 + r)*512 + c);
      }
    }
    return;
  }

  // ---- wave 0: invert A11 in registers, lane = row ----
  const int lane = tid;
  float w[64];
  {
    const float* src = Mg + (size_t)(k0 + lane)*512 + k0;
#pragma unroll
    for (int q = 0; q < 16; ++q) {
      const float4 t4 = *(const float4*)(src + q*4);
      w[q*4+0]=t4.x; w[q*4+1]=t4.y; w[q*4+2]=t4.z; w[q*4+3]=t4.w;
    }
  }

  float fcur = w[0];                      // = w[kk] at loop top (own column kk)
#pragma unroll 1
  for (int kk = 0; kk < 64; ++kk) {
    const float pv = __shfl(fcur, kk);    // old M[kk][kk]
    const float p  = 1.0f / pv;
    const float fp = fcur * p;
    const bool isp = (lane == kk);
    const float alpha = isp ? p : -fp;    // also the new w[kk] value
    const float beta  = isp ? 0.0f : 1.0f;
    float fnext = fcur;
#pragma unroll
    for (int j = 0; j < 64; ++j) {
      const float rj = __shfl(w[j], kk);  // old pivot-row value M[kk][j]
      float nv = fmaf(alpha, rj, beta * w[j]);
      // pivot lane: alpha*rj = p*w[j]; others: w[j] - fp*rj
      const float val = (j == kk) ? alpha : nv;
      if (j == kk + 1) fnext = val;       // uniform cond, select
      w[j] = val;
    }
    fcur = fnext;
  }

  {
    float* dst = Ig + lane*64;
#pragma unroll
    for (int q = 0; q < 16; ++q)
      *(float4*)(dst + q*4) = make_float4(w[q*4+0], w[q*4+1], w[q*4+2], w[q*4+3]);
  }
}

// gj_w: W = -C * A11inv (off-panel rows) / A11inv (panel rows), written into
// the panel columns of M. Tiles 128 rows x 64 cols, K=64 in chunks of 16.
__global__ __launch_bounds__(256) void gj_w_kernel(
    float* __restrict__ M, const float* __restrict__ Inv, int k0)
{
  const int bh = blockIdx.y;
  const int row0 = blockIdx.x * 128;
  float* const Mg = M + (size_t)bh*262144;
  const float* const Ig = Inv + (size_t)bh*4096;

  __shared__ __align__(16) float Ct[16*132];
  __shared__ __align__(16) float It[16*68];

  const int tx = threadIdx.x, ty = threadIdx.y;   // (16,16)
  const int tid = ty*16 + tx;
  const int lt = tid & 15, lr = tid >> 4;

  float acc[8][4] = {};

  for (int kc = 0; kc < 64; kc += 16) {
#pragma unroll
    for (int u = 0; u < 8; ++u) {
      const int r = lr + 16*u;
      Ct[lt*132 + r] = Mg[(size_t)(row0 + r)*512 + k0 + kc + lt];   // C slice
    }
    {
      const int j = tid & 63, t0 = tid >> 6;      // t0 = 0..3
#pragma unroll
      for (int u = 0; u < 4; ++u) {
        const int t = t0*4 + u;
        It[t*68 + j] = Ig[(kc + t)*64 + j];
      }
    }
    __syncthreads();
#pragma unroll
    for (int t = 0; t < 16; ++t) {
      const float4 a0 = *(const float4*)(Ct + t*132 + ty*8);
      const float4 a1 = *(const float4*)(Ct + t*132 + ty*8 + 4);
      const float4 b  = *(const float4*)(It + t*68 + tx*4);
      const float a[8] = {a0.x,a0.y,a0.z,a0.w,a1.x,a1.y,a1.z,a1.w};
      const float bb[4] = {b.x,b.y,b.z,b.w};
#pragma unroll
      for (int i = 0; i < 8; ++i)
#pragma unroll
        for (int j = 0; j < 4; ++j)
          acc[i][j] = fmaf(a[i], bb[j], acc[i][j]);
    }
    __syncthreads();
  }

#pragma unroll
  for (int i = 0; i < 8; ++i) {
    const int irow = row0 + ty*8 + i;
    float4 v;
    if (irow >= k0 && irow < k0 + 64) {
      v = *(const float4*)(Ig + (irow - k0)*64 + tx*4);   // A11inv rows
    } else {
      v = make_float4(-acc[i][0], -acc[i][1], -acc[i][2], -acc[i][3]);
    }
    *(float4*)(Mg + (size_t)irow*512 + k0 + tx*4) = v;
  }
}

// Update: M[i][j] = (i in P ? 0 : M_old[i][j]) + W[i][:] . Mp_old[:][j]
__global__ __launch_bounds__(256) void gj_update_kernel(
    float* __restrict__ M, const float* __restrict__ Mp, int k0)
{
  const int bh = blockIdx.z;
  const int row0 = blockIdx.y * 128, col0 = blockIdx.x * 128;
  float* const Mg = M + (size_t)bh*262144;
  const float* const Mpg = Mp + (size_t)bh*32768;

  __shared__ __align__(16) float At[16*132];
  __shared__ __align__(16) float Bt[16*132];
  const int tx = threadIdx.x, ty = threadIdx.y;
  const int tid = ty*16 + tx;
  const int lt = tid & 15, lr = tid >> 4;
  const int bc = tid & 127, btr = tid >> 7;

  float acc[8][8] = {};

  for (int kc = 0; kc < 64; kc += 16) {
#pragma unroll
    for (int u = 0; u < 8; ++u) {
      const int r = lr + 16*u;
      At[lt*132 + r] = Mg[(size_t)(row0 + r)*512 + k0 + kc + lt];     // W slice
    }
#pragma unroll
    for (int u = 0; u < 8; ++u) {
      const int t = btr + 2*u;
      Bt[t*132 + bc] = Mpg[(size_t)(kc + t)*512 + col0 + bc];         // Mp_old
    }
    __syncthreads();
    mm_micro(At, Bt, acc, tx, ty);
    __syncthreads();
  }

#pragma unroll
  for (int ii = 0; ii < 8; ++ii) {
    const int irow = row0 + ty*8 + ii;
    const bool inP = (irow >= k0) && (irow < k0 + 64);
#pragma unroll
    for (int jj = 0; jj < 8; jj += 4) {
      const int jcol = col0 + tx*8 + jj;
      if (jcol >= k0 && jcol < k0 + 64) continue;   // panel cols hold W
      float* cell = Mg + (size_t)irow*512 + jcol;
      float4 v = make_float4(acc[ii][jj+0], acc[ii][jj+1], acc[ii][jj+2], acc[ii][jj+3]);
      if (!inP) {
        const float4 o = *(const float4*)cell;
        v.x += o.x; v.y += o.y; v.z += o.z; v.w += o.w;
      }
      *(float4*)cell = v;
    }
  }
}

// ---------------------------------------------------------------------------
// diag = diag(LLinv); d0 = R * diag
__global__ void diag_d0_kernel(const float* __restrict__ Minv, const float* __restrict__ Rv,
                               float* __restrict__ diagv, float* __restrict__ d0)
{
  const int bh = blockIdx.x, l = threadIdx.x;
  const float dg = Minv[(size_t)bh*262144 + (size_t)l*513];
  diagv[bh*512 + l] = dg;
  d0[bh*512 + l] = Rv[(bh/12)*512 + l] * dg;
}

// ---------------------------------------------------------------------------
// loss = mean_n( label_n * sum_h -log(clip(d0[b,h,l], 1e-5, 1-1e-5)) )
__global__ __launch_bounds__(1024) void loss_kernel(const float* __restrict__ d0,
                                                    const int* __restrict__ labels,
                                                    float* __restrict__ loss)
{
  float acc = 0.0f;
  for (int n = threadIdx.x; n < 4096; n += 1024) {
    if (labels[n] != 0) {
      const int b = n >> 9, l = n & 511;
      float s = 0.0f;
#pragma unroll
      for (int h = 0; h < 12; ++h) {
        float p = d0[(size_t)(b*12 + h)*512 + l];
        p = fminf(fmaxf(p, 1e-5f), 1.0f - 1e-5f);
        s -= logf(p);
      }
      acc += s;
    }
  }
  __shared__ float red[16];
#pragma unroll
  for (int off = 32; off > 0; off >>= 1) acc += __shfl_down(acc, off, 64);
  const int wv = threadIdx.x >> 6, ln = threadIdx.x & 63;
  if (ln == 0) red[wv] = acc;
  __syncthreads();
  if (threadIdx.x == 0) {
    float t = 0.0f;
    for (int w2 = 0; w2 < 16; ++w2) t += red[w2];
    loss[0] = t * (1.0f/4096.0f);
  }
}

// ---------------------------------------------------------------------------
// d[i][j] = A[i][j] * (diag[j] - LLinv[j][i])   (in place over A)
__global__ __launch_bounds__(256) void finalize_d_kernel(
    float* __restrict__ dmat, const float* __restrict__ Minv, const float* __restrict__ diagv)
{
  const int bh = blockIdx.z;
  const int i0 = blockIdx.y*64, j0 = blockIdx.x*64;
  __shared__ float t[64][65];
  const int tx = threadIdx.x, ty = threadIdx.y;
  const size_t mbase = (size_t)bh*262144;
  for (int jj = ty; jj < 64; jj += 4)
    t[jj][tx] = Minv[mbase + (size_t)(j0+jj)*512 + i0 + tx];
  __syncthreads();
  const float dg_j = diagv[bh*512 + j0 + tx];
  for (int ii = ty; ii < 64; ii += 4) {
    const size_t idx = mbase + (size_t)(i0+ii)*512 + j0 + tx;
    dmat[idx] = dmat[idx] * (dg_j - t[tx][ii]);
  }
}

// ---------------------------------------------------------------------------
// context[b,h,q,:] = sum_k attn[q,k] * x[b,k,:],  attn[q,k] = masked d[k,q]
// MFMA version: bf16 hi/lo split, 3 products (hh, hl, lh) per 16x16x32 tile.
__device__ __forceinline__ unsigned int pack_bf16x2(float v)
{
  const unsigned int u = __float_as_uint(v);
  const unsigned int hi = (u + 0x7FFFu + ((u >> 16) & 1u)) >> 16;  // RNE bf16(v)
  const float hf = __uint_as_float(hi << 16);
  const unsigned int lo = __float_as_uint(v - hf) >> 16;           // trunc bf16(residual)
  return hi | (lo << 16);
}

__global__ __launch_bounds__(256) void context_mfma_kernel(
    const float* __restrict__ dmat, const float* __restrict__ x,
    const float* __restrict__ mv, float* __restrict__ ctx)
{
  const int bh = blockIdx.z, b = bh / 12;
  const int q0 = blockIdx.y << 7;          // 0..384
  const int c0 = blockIdx.x << 7;          // 0..640

  __shared__ unsigned int As[32*133];      // packed (hi|lo) of masked d^T tile cols
  __shared__ unsigned int Bs[32*133];      // packed (hi|lo) of x tile cols

  const int tid = threadIdx.x;
  const int w = tid >> 6, l = tid & 63;
  const int wq = w >> 1, wc = w & 1;       // wave -> 64x64 quadrant
  const int l15 = l & 15, g = l >> 4;      // MFMA lane coords
  const int q4 = tid & 31, kr0 = tid >> 5; // staging coords

  const size_t dbase = (size_t)bh*262144;
  const size_t xbase = (size_t)b*393216;   // 512*768

  float mq[4];
  {
    const float4 t4 = *(const float4*)(mv + b*512 + q0 + q4*4);
    mq[0]=t4.x; mq[1]=t4.y; mq[2]=t4.z; mq[3]=t4.w;
  }

  f32x4 acc[4][4] = {};

  for (int kk = 0; kk < 512; kk += 32) {
    __syncthreads();                       // previous iter's frag reads done
#pragma unroll
    for (int p = 0; p < 4; ++p) {
      const int kr = kr0 + 8*p;
      const int krow = kk + kr;
      const float mk = mv[b*512 + krow];
      const float4 av = *(const float4*)(dmat + dbase + (size_t)krow*512 + q0 + q4*4);
      const float4 bv = *(const float4*)(x + xbase + (size_t)krow*768 + c0 + q4*4);
      unsigned int* aw = As + kr*133 + q4*4;
      unsigned int* bw = Bs + kr*133 + q4*4;
      aw[0] = pack_bf16x2(((mk + mq[0]) != 0.0f) ? 0.0f : av.x);
      aw[1] = pack_bf16x2(((mk + mq[1]) != 0.0f) ? 0.0f : av.y);
      aw[2] = pack_bf16x2(((mk + mq[2]) != 0.0f) ? 0.0f : av.z);
      aw[3] = pack_bf16x2(((mk + mq[3]) != 0.0f) ? 0.0f : av.w);
      bw[0] = pack_bf16x2(bv.x);
      bw[1] = pack_bf16x2(bv.y);
      bw[2] = pack_bf16x2(bv.z);
      bw[3] = pack_bf16x2(bv.w);
    }
    __syncthreads();

    u32x4 ah[4], al[4], bhv[4], blv[4];
#pragma unroll
    for (int mi = 0; mi < 4; ++mi) {
      const unsigned int* base = As + g*8*133 + (wq*64 + mi*16 + l15);
      unsigned int u[8];
#pragma unroll
      for (int e = 0; e < 8; ++e) u[e] = base[e*133];
#pragma unroll
      for (int d2 = 0; d2 < 4; ++d2) {
        ah[mi][d2] = __builtin_amdgcn_perm(u[2*d2+1], u[2*d2], 0x05040100u);
        al[mi][d2] = __builtin_amdgcn_perm(u[2*d2+1], u[2*d2], 0x07060302u);
      }
    }
#pragma unroll
    for (int ni = 0; ni < 4; ++ni) {
      const unsigned int* base = Bs + g*8*133 + (wc*64 + ni*16 + l15);
      unsigned int u[8];
#pragma unroll
      for (int e = 0; e < 8; ++e) u[e] = base[e*133];
#pragma unroll
      for (int d2 = 0; d2 < 4; ++d2) {
        bhv[ni][d2] = __builtin_amdgcn_perm(u[2*d2+1], u[2*d2], 0x05040100u);
        blv[ni][d2] = __builtin_amdgcn_perm(u[2*d2+1], u[2*d2], 0x07060302u);
      }
    }

#pragma unroll
    for (int mi = 0; mi < 4; ++mi) {
      const bf16x8 Ah = __builtin_bit_cast(bf16x8, ah[mi]);
      const bf16x8 Al = __builtin_bit_cast(bf16x8, al[mi]);
#pragma unroll
      for (int ni = 0; ni < 4; ++ni) {
        const bf16x8 Bh = __builtin_bit_cast(bf16x8, bhv[ni]);
        const bf16x8 Bl = __builtin_bit_cast(bf16x8, blv[ni]);
        acc[mi][ni] = __builtin_amdgcn_mfma_f32_16x16x32_bf16(Ah, Bh, acc[mi][ni], 0, 0, 0);
        acc[mi][ni] = __builtin_amdgcn_mfma_f32_16x16x32_bf16(Ah, Bl, acc[mi][ni], 0, 0, 0);
        acc[mi][ni] = __builtin_amdgcn_mfma_f32_16x16x32_bf16(Al, Bh, acc[mi][ni], 0, 0, 0);
      }
    }
  }

#pragma unroll
  for (int mi = 0; mi < 4; ++mi) {
    const int row = q0 + wq*64 + mi*16 + g*4;
#pragma unroll
    for (int ni = 0; ni < 4; ++ni) {
      const int col = c0 + wc*64 + ni*16 + l15;
#pragma unroll
      for (int r = 0; r < 4; ++r)
        ctx[((size_t)bh*512 + row + r)*768 + col] = acc[mi][ni][r];
    }
  }
}

// ---------------------------------------------------------------------------
extern "C" void kernel_launch(void* const* d_in, const int* in_sizes, int n_in,
                              void* d_out, int out_size, void* d_ws, size_t ws_size,
                              hipStream_t stream)
{
  (void)in_sizes; (void)n_in; (void)out_size; (void)ws_size;

  const float* x    = (const float*)d_in[0];
  const float* mask = (const float*)d_in[1];
  const int*   roots= (const int*)d_in[2];
  const float* Wq   = (const float*)d_in[4];
  const float* bq   = (const float*)d_in[5];
  const float* Wk   = (const float*)d_in[6];
  const float* bk   = (const float*)d_in[7];
  const float* Wr   = (const float*)d_in[8];
  const float* br   = (const float*)d_in[9];

  float* out        = (float*)d_out;
  float* ctx_region = out;                 // 37748736 floats
  float* d_region   = out + 37748736;      // 25165824 floats (A -> d in place)
  float* d0_region  = out + 62914560;      // 49152 floats
  float* loss_ptr   = out + 62963712;      // 1 float

  // scratch inside the context region (overwritten by context_mfma at the end)
  float* Qs = ctx_region;                  // 3145728
  float* Ks = ctx_region + 3145728;        // 3145728
  float* Mv = ctx_region + 6291456;        // 25165824 (ends at 31457280)
  float* Mp = ctx_region + 31457280;       // 3145728  (ends at 34603008)
  float* Invs = ctx_region + 34603008;     // 393216   (ends at 34996224 < 37748736)

  float* ws     = (float*)d_ws;
  float* Rv     = ws;                      // 4096
  float* mv     = ws + 4096;               // 4096
  float* colsum = ws + 8192;               // 49152
  float* diagv  = ws + 57344;              // 49152

  proj_kernel   <<<dim3(6,32,2),  dim3(16,16), 0, stream>>>(x, Wq, bq, Wk, bk, Qs, Ks);
  root_kernel   <<<dim3(1024),    dim3(256),   0, stream>>>(x, Wr, br, mask, Rv, mv);
  scores_kernel <<<dim3(4,4,96),  dim3(16,16), 0, stream>>>(Qs, Ks, mv, d_region);
  colsum_kernel <<<dim3(2,96),    dim3(256),   0, stream>>>(d_region, colsum);
  buildM_kernel <<<dim3(24576),   dim3(256),   0, stream>>>(d_region, colsum, Rv, Mv);

  for (int step = 0; step < 8; ++step) {
    const int k0 = step * 64;
    gj_inv_kernel   <<<dim3(96),     dim3(256),   0, stream>>>(Mv, Mp, Invs, k0);
    gj_w_kernel     <<<dim3(4,96),   dim3(16,16), 0, stream>>>(Mv, Invs, k0);
    gj_update_kernel<<<dim3(4,4,96), dim3(16,16), 0, stream>>>(Mv, Mp, k0);
  }

  diag_d0_kernel<<<dim3(96),      dim3(512),   0, stream>>>(Mv, Rv, diagv, d0_region);
  loss_kernel   <<<dim3(1),       dim3(1024),  0, stream>>>(d0_region, roots, loss_ptr);
  finalize_d_kernel<<<dim3(8,8,96), dim3(64,4), 0, stream>>>(d_region, Mv, diagv);
  context_mfma_kernel<<<dim3(6,4,96), dim3(256), 0, stream>>>(d_region, x, mv, ctx_region);
}